// Round 4
// baseline (196.514 us; speedup 1.0000x reference)
//
#include <hip/hip_runtime.h>
#include <math.h>

#define K_RBF 32
#define H_DIM 64
#define TBL 4096
#define D_MAX 16.0f
#define N_NODES 49152
#define N_EDGES 786432
#define N_GRAPHS 8
#define NODES_PER_GRAPH 6144
#define EV_A3_TO_GPA 160.21766208f
#define LOG2E 1.44269504088896f

// out layout: energies[8] | forces[147456] | stresses[72] | hessian[1]
#define OUT_FORCES 8
#define OUT_STRESS 147464
#define OUT_TAIL_N 81

// force binning: 256 chunks x 192 nodes
#define CHUNK_NODES  192
#define CHUNK_FLOATS 576
#define N_CHUNKS     256
#define REC_CAP      7168        // mean 6144, sigma ~78 -> +13 sigma

// fused kernel geometry: 256 blocks x 1024 thr, 1 block/CU (co-resident by
// construction: LDS ~28.5 KB, VGPR<=128 via launch_bounds -> 16 waves/CU).
#define FUSED_BLOCKS  256
#define FUSED_THREADS 1024
#define EDGES_PER_BLOCK 3072                   // 786432 / 256
#define EDGES_PER_GRAPH (N_EDGES / N_GRAPHS)   // 98304
#define BLK_PER_GRAPH 32                       // 98304 / 3072
#define TBL_PER_BLOCK 16                       // 4096 / 256

// ws layout (bytes): tab 32 KB | gcnt 1 KB | done 1 KB | records 29.4 MB
#define OFF_TAB  0u
#define OFF_CNT  32768u
#define OFF_DONE 33792u
#define OFF_REC  34816u
#define WS_NEED (OFF_REC + (size_t)N_CHUNKS * REC_CAP * 16u)

// chunk index: node/192 = (node>>6)/3 via mul-shift (exact for node < 49152)
__device__ __forceinline__ int chunk_of(int node) {
    return (int)((unsigned)((node >> 6) * 683) >> 11);
}

// -------- shared MLP-table entry math (wave-per-entry) ----------------------
__device__ __forceinline__ float2 mlp_entry(
    int i, int lane, const float* __restrict__ centers,
    const float* __restrict__ W1, const float* __restrict__ b1,
    const float* __restrict__ W2s, const float* __restrict__ b2,
    const float* __restrict__ W3, const float* __restrict__ b3)
{
    float d  = (float)i * (D_MAX / (float)TBL);
    float z1 = b1[lane], u = 0.f;
#pragma unroll
    for (int k = 0; k < K_RBF; ++k) {
        float tc = d - centers[k];
        float e  = exp2f(-tc * tc * LOG2E);       // exp(-t^2)
        float w  = W1[k * H_DIM + lane];
        z1 = fmaf(e, w, z1);
        u  = fmaf(-2.f * tc * e, w, u);
    }
    float s1  = 1.f / (1.f + exp2f(-z1 * LOG2E));
    float h1  = z1 * s1;
    float ds1 = s1 * fmaf(z1, 1.f - s1, 1.f);     // silu'(z1)

    float z2 = b2[lane];
#pragma unroll
    for (int h = 0; h < H_DIM; ++h)
        z2 = fmaf(__shfl(h1, h, 64), W2s[h * 65 + lane], z2);

    float s2  = 1.f / (1.f + exp2f(-z2 * LOG2E));
    float w3  = W3[lane];
    float Fp  = z2 * s2 * w3;
    float dz2 = w3 * s2 * fmaf(z2, 1.f - s2, 1.f);

    float dh1 = 0.f;
#pragma unroll
    for (int j = 0; j < H_DIM; ++j)
        dh1 = fmaf(__shfl(dz2, j, 64), W2s[lane * 65 + j], dh1);

    float Gp = dh1 * ds1 * u;
#pragma unroll
    for (int m = 32; m > 0; m >>= 1) {
        Fp += __shfl_xor(Fp, m, 64);
        Gp += __shfl_xor(Gp, m, 64);
    }
    return make_float2(Fp + b3[0], Gp);
}

// -------- Fused kernel: table -> spin -> edges+emit -> spin -> scatter ------
// Grid 256 = #CUs; all blocks co-resident (1/CU), so device-scope spin
// barriers are deadlock-free. done[0] zeroed by a 4-byte memset pre-launch;
// done[1], gcnt, out-tail zeroed by block 0 BEFORE its done[0] increment.
__global__ __launch_bounds__(FUSED_THREADS, 4) void fused_all(
    const float* __restrict__ pos, const float* __restrict__ bond,
    const int* __restrict__ src, const int* __restrict__ dst,
    const float* __restrict__ volume, const float* __restrict__ centers,
    const float* __restrict__ W1, const float* __restrict__ b1,
    const float* __restrict__ W2, const float* __restrict__ b2,
    const float* __restrict__ W3, const float* __restrict__ b3,
    float2* __restrict__ tab, int* __restrict__ gcnt, int* __restrict__ done,
    float4* __restrict__ recs, float* __restrict__ out)
{
    __shared__ float W2s[H_DIM * 65];          // 16.6 KB
    __shared__ int   cntl[N_CHUNKS];           // 1 KB
    __shared__ int   basech[N_CHUNKS];         // 1 KB
    __shared__ float red[16][10];              // 640 B
    __shared__ float acc[4 * 577];             // 9.2 KB, bank-rotated replicas

    const int t = threadIdx.x;
    const int b = blockIdx.x;
    const int lane = t & 63, wv = t >> 6;

    // ---- Phase T: build 16 table entries + block-0 housekeeping ----
    for (int idx = t; idx < H_DIM * H_DIM; idx += FUSED_THREADS)
        W2s[(idx >> 6) * 65 + (idx & 63)] = W2[idx];
    if (b == 0) {
        if (t < N_CHUNKS) gcnt[t] = 0;
        if (t == 512) done[1] = 0;
        if (t < N_GRAPHS) out[t] = 0.f;                       // energies
        else if (t >= 8 && t < OUT_TAIL_N) out[OUT_STRESS + t - 8] = 0.f;
    }
    __syncthreads();

    {
        int i = b * TBL_PER_BLOCK + wv;
        float2 fg = mlp_entry(i, lane, centers, W1, b1, W2s, b2, W3, b3);
        if (lane == 0) tab[i] = fg;
    }
    __syncthreads();   // drains the tab store (vmcnt 0 at barrier)

    // ---- spin barrier 1: table + housekeeping visible device-wide ----
    if (t == 0) {
        __hip_atomic_fetch_add(&done[0], 1, __ATOMIC_RELEASE,
                               __HIP_MEMORY_SCOPE_AGENT);
        while (__hip_atomic_load(&done[0], __ATOMIC_ACQUIRE,
                                 __HIP_MEMORY_SCOPE_AGENT) < FUSED_BLOCKS)
            __builtin_amdgcn_s_sleep(2);
    }
    __syncthreads();

    // ---- Phase E: 3072 edges, record emission (R0-style, no sort) ----
    if (t < N_CHUNKS) cntl[t] = 0;
    __syncthreads();

    const int g = b >> 5;                      // 8 graphs x 32 blocks
    const int w = b & 31;
    const int base_e = g * EDGES_PER_GRAPH + w * EDGES_PER_BLOCK;

    float vacc[10];
#pragma unroll
    for (int q = 0; q < 10; ++q) vacc[q] = 0.f;

    int   edi[3], esi[3], es0[3], es1[3];
    float egx[3], egy[3], egz[3];

#pragma unroll
    for (int i = 0; i < 3; ++i) {
        int e  = base_e + i * FUSED_THREADS + t;
        int si = src[e], di = dst[e];
        float bx = bond[3 * e + 0], by = bond[3 * e + 1], bz = bond[3 * e + 2];
        float dx = bx + pos[3 * di + 0] - pos[3 * si + 0];
        float dy = by + pos[3 * di + 1] - pos[3 * si + 1];
        float dz = bz + pos[3 * di + 2] - pos[3 * si + 2];
        float d  = sqrtf(fmaf(dx, dx, fmaf(dy, dy, fmaf(dz, dz, 1e-12f))));

        float tt  = fminf(d * ((float)TBL / D_MAX), (float)(TBL - 1));
        int   ix  = min((int)tt, TBL - 2);
        float fr  = tt - (float)ix;
        float2 ta = tab[ix], tb2 = tab[ix + 1];
        float F = fmaf(fr, tb2.x - ta.x, ta.x);
        float G = fmaf(fr, tb2.y - ta.y, ta.y);

        float scl = G / d;                     // gbv = (dE/dd)/d * disp
        float gx = scl * dx, gy = scl * dy, gz = scl * dz;
        egx[i] = gx; egy[i] = gy; egz[i] = gz;
        edi[i] = di; esi[i] = si;
        es0[i] = atomicAdd(&cntl[chunk_of(di)], 1);
        es1[i] = atomicAdd(&cntl[chunk_of(si)], 1);

        vacc[0] += F;
        vacc[1] = fmaf(bx, gx, vacc[1]); vacc[2] = fmaf(bx, gy, vacc[2]);
        vacc[3] = fmaf(bx, gz, vacc[3]); vacc[4] = fmaf(by, gx, vacc[4]);
        vacc[5] = fmaf(by, gy, vacc[5]); vacc[6] = fmaf(by, gz, vacc[6]);
        vacc[7] = fmaf(bz, gx, vacc[7]); vacc[8] = fmaf(bz, gy, vacc[8]);
        vacc[9] = fmaf(bz, gz, vacc[9]);
    }
    __syncthreads();
    if (t < N_CHUNKS) basech[t] = atomicAdd(&gcnt[t], cntl[t]);
    __syncthreads();

#pragma unroll
    for (int i = 0; i < 3; ++i) {
        int c0 = chunk_of(edi[i]), c1 = chunk_of(esi[i]);
        int l0 = edi[i] - c0 * CHUNK_NODES;
        int l1 = esi[i] - c1 * CHUNK_NODES;
        int p0 = basech[c0] + es0[i];
        int p1 = basech[c1] + es1[i];
        if (p0 < REC_CAP)   // dst gets -g (forces = -gpos)
            recs[(size_t)c0 * REC_CAP + p0] =
                make_float4(-egx[i], -egy[i], -egz[i], __int_as_float(l0));
        if (p1 < REC_CAP)   // src gets +g
            recs[(size_t)c1 * REC_CAP + p1] =
                make_float4(egx[i], egy[i], egz[i], __int_as_float(l1));
    }

    // block-level energy+stress reduce (all edges in block share graph g)
#pragma unroll
    for (int q = 0; q < 10; ++q) {
        float x = vacc[q];
#pragma unroll
        for (int m = 32; m > 0; m >>= 1) x += __shfl_xor(x, m, 64);
        vacc[q] = x;
    }
    if (lane == 0)
#pragma unroll
        for (int q = 0; q < 10; ++q) red[wv][q] = vacc[q];
    __syncthreads();
    if (t < 10) {
        float tot = 0.f;
#pragma unroll
        for (int k = 0; k < 16; ++k) tot += red[k][t];
        if (t == 0) atomicAdd(out + g, tot);
        else {
            float vol = volume[g * NODES_PER_GRAPH];
            atomicAdd(out + OUT_STRESS + g * 9 + (t - 1),
                      tot * (EV_A3_TO_GPA / vol));
        }
    }
    __syncthreads();   // drain record stores before publishing

    // ---- spin barrier 2: all records visible device-wide ----
    if (t == 0) {
        __hip_atomic_fetch_add(&done[1], 1, __ATOMIC_RELEASE,
                               __HIP_MEMORY_SCOPE_AGENT);
        while (__hip_atomic_load(&done[1], __ATOMIC_ACQUIRE,
                                 __HIP_MEMORY_SCOPE_AGENT) < FUSED_BLOCKS)
            __builtin_amdgcn_s_sleep(2);
    }
    __syncthreads();

    // ---- Phase S: scatter chunk b with 4-replica LDS accumulators ----
    for (int j = t; j < 4 * 577; j += FUSED_THREADS) acc[j] = 0.f;
    __syncthreads();

    {
        const int c = b;
        int total = min(gcnt[c], REC_CAP);
        const float4* seg = recs + (size_t)c * REC_CAP;
        const int rep = (t & 3) * 577;        // 577 % 32 == 1: bank-rotated
        for (int r = t; r < total; r += FUSED_THREADS) {
            float4 rec = seg[r];
            int li = 3 * __float_as_int(rec.w);
            atomicAdd(&acc[rep + li + 0], rec.x);
            atomicAdd(&acc[rep + li + 1], rec.y);
            atomicAdd(&acc[rep + li + 2], rec.z);
        }
        __syncthreads();
        if (t < CHUNK_FLOATS) {
            float s = acc[t] + acc[577 + t] + acc[2 * 577 + t] + acc[3 * 577 + t];
            out[OUT_FORCES + c * CHUNK_FLOATS + t] = s;
        }
    }
}

// -------- Fallback-path kernels (ws too small): table + device atomics -----
__global__ __launch_bounds__(256) void build_table(
    const float* __restrict__ centers,
    const float* __restrict__ W1, const float* __restrict__ b1,
    const float* __restrict__ W2, const float* __restrict__ b2,
    const float* __restrict__ W3, const float* __restrict__ b3,
    float2* __restrict__ tab)
{
    __shared__ float W2s[H_DIM * 65];
    for (int idx = threadIdx.x; idx < H_DIM * H_DIM; idx += 256)
        W2s[(idx >> 6) * 65 + (idx & 63)] = W2[idx];
    __syncthreads();

    int lane = threadIdx.x & 63;
    int i    = blockIdx.x * 4 + (threadIdx.x >> 6);
    float2 fg = mlp_entry(i, lane, centers, W1, b1, W2s, b2, W3, b3);
    if (lane == 0) tab[i] = fg;
}

__global__ __launch_bounds__(256) void edge_fallback(
    const float* __restrict__ pos, const float* __restrict__ bond,
    const int* __restrict__ src, const int* __restrict__ dst,
    const float* __restrict__ volume, const float2* __restrict__ tab,
    float* __restrict__ out)
{
    __shared__ float red[4][10];
    int lb = (blockIdx.x & 7) * (EDGES_PER_GRAPH / 256) + (blockIdx.x >> 3);
    int g  = blockIdx.x & 7;
    int e  = lb * 256 + threadIdx.x;

    int si = src[e], di = dst[e];
    float bx = bond[3 * e + 0], by = bond[3 * e + 1], bz = bond[3 * e + 2];
    float dx = bx + pos[3 * di + 0] - pos[3 * si + 0];
    float dy = by + pos[3 * di + 1] - pos[3 * si + 1];
    float dz = bz + pos[3 * di + 2] - pos[3 * si + 2];
    float d  = sqrtf(fmaf(dx, dx, fmaf(dy, dy, fmaf(dz, dz, 1e-12f))));

    float tt  = fminf(d * ((float)TBL / D_MAX), (float)(TBL - 1));
    int   ix  = min((int)tt, TBL - 2);
    float fr  = tt - (float)ix;
    float2 ta = tab[ix], tb2 = tab[ix + 1];
    float F = fmaf(fr, tb2.x - ta.x, ta.x);
    float G = fmaf(fr, tb2.y - ta.y, ta.y);
    float scl = G / d;
    float gx = scl * dx, gy = scl * dy, gz = scl * dz;

    float* forces = out + OUT_FORCES;
    atomicAdd(forces + 3 * di + 0, -gx);
    atomicAdd(forces + 3 * di + 1, -gy);
    atomicAdd(forces + 3 * di + 2, -gz);
    atomicAdd(forces + 3 * si + 0,  gx);
    atomicAdd(forces + 3 * si + 1,  gy);
    atomicAdd(forces + 3 * si + 2,  gz);

    float v[10] = { F,
                    bx * gx, bx * gy, bx * gz,
                    by * gx, by * gy, by * gz,
                    bz * gx, bz * gy, bz * gz };
#pragma unroll
    for (int q = 0; q < 10; ++q) {
        float x = v[q];
#pragma unroll
        for (int m = 32; m > 0; m >>= 1) x += __shfl_xor(x, m, 64);
        v[q] = x;
    }
    int wave = threadIdx.x >> 6;
    if ((threadIdx.x & 63) == 0)
#pragma unroll
        for (int q = 0; q < 10; ++q) red[wave][q] = v[q];
    __syncthreads();
    if (threadIdx.x < 10) {
        float tot = red[0][threadIdx.x] + red[1][threadIdx.x]
                  + red[2][threadIdx.x] + red[3][threadIdx.x];
        if (threadIdx.x == 0) atomicAdd(out + g, tot);
        else {
            float vol = volume[g * NODES_PER_GRAPH];
            atomicAdd(out + OUT_STRESS + g * 9 + (threadIdx.x - 1),
                      tot * (EV_A3_TO_GPA / vol));
        }
    }
}

extern "C" void kernel_launch(void* const* d_in, const int* in_sizes, int n_in,
                              void* d_out, int out_size, void* d_ws, size_t ws_size,
                              hipStream_t stream)
{
    const float* pos     = (const float*)d_in[0];
    const float* bond    = (const float*)d_in[1];
    const int*   src     = (const int*)d_in[2];
    const int*   dst     = (const int*)d_in[3];
    // d_in[4] = edge_graph (implicit: edges contiguous per graph)
    const float* volume  = (const float*)d_in[5];
    const float* centers = (const float*)d_in[6];
    const float* W1 = (const float*)d_in[7];
    const float* b1 = (const float*)d_in[8];
    const float* W2 = (const float*)d_in[9];
    const float* b2 = (const float*)d_in[10];
    const float* W3 = (const float*)d_in[11];
    const float* b3 = (const float*)d_in[12];
    float*  out  = (float*)d_out;
    char*   ws   = (char*)d_ws;
    float2* tab  = (float2*)(ws + OFF_TAB);
    int*    gcnt = (int*)(ws + OFF_CNT);
    int*    done = (int*)(ws + OFF_DONE);
    float4* recs = (float4*)(ws + OFF_REC);

    if (ws_size >= WS_NEED) {
        hipMemsetAsync(done, 0, 4, stream);    // done[0]; done[1] zeroed in-kernel
        fused_all<<<FUSED_BLOCKS, FUSED_THREADS, 0, stream>>>(
            pos, bond, src, dst, volume, centers,
            W1, b1, W2, b2, W3, b3, tab, gcnt, done, recs, out);
    } else {
        hipMemsetAsync(d_out, 0, (size_t)out_size * sizeof(float), stream);
        build_table<<<TBL / 4, 256, 0, stream>>>(centers, W1, b1, W2, b2, W3, b3, tab);
        edge_fallback<<<N_EDGES / 256, 256, 0, stream>>>(
            pos, bond, src, dst, volume, tab, out);
    }
}

// Round 6
// 159.607 us; speedup vs baseline: 1.2312x; 1.2312x over previous
//
#include <hip/hip_runtime.h>
#include <math.h>

#define K_RBF 32
#define H_DIM 64
#define TBL 4096
#define D_MAX 16.0f
#define N_NODES 49152
#define N_EDGES 786432
#define N_GRAPHS 8
#define NODES_PER_GRAPH 6144
#define EV_A3_TO_GPA 160.21766208f
#define LOG2E 1.44269504088896f

// out layout: energies[8] | forces[147456] | stresses[72] | hessian[1]
#define OUT_FORCES 8
#define OUT_STRESS 147464
#define OUT_TAIL_N 81

// force binning: 256 chunks x 192 nodes
#define CHUNK_NODES  192
#define CHUNK_FLOATS 576
#define N_CHUNKS     256

// edge geometry: 1536 blocks x 512 thr x 1 edge -> up to 4 blocks/CU
#define EDGE_BLOCKS   1536
#define EDGE_THREADS  512
#define EDGES_PER_GRAPH (N_EDGES / N_GRAPHS)   // 98304
#define BLK_PER_GRAPH 192                      // 98304 / 512

// static slot ownership: recs[chunk][block][SLOT_CAP]; per-(c,b) lambda = 4
// (1024 records / 256 chunks), Poisson tail beyond 32 ~ 1e-20 -> no global
// atomics, no cross-block slot exchange, no base barrier.
#define SLOT_CAP   32
#define CAP_SHIFT  5

// ws layout (bytes): tab 32 KB | cnttab 1.5 MB | records 201.3 MB
#define OFF_TAB 0u
#define OFF_CNT 32768u
#define OFF_REC (32768u + (unsigned)(N_CHUNKS * EDGE_BLOCKS * 4))   // 1605632
#define WS_NEED ((size_t)OFF_REC + (size_t)N_CHUNKS * EDGE_BLOCKS * SLOT_CAP * 16u)

// chunk index: node/192 = (node>>6)/3 via mul-shift (exact for node < 49152)
__device__ __forceinline__ int chunk_of(int node) {
    return (int)((unsigned)((node >> 6) * 683) >> 11);
}

// -------- shared MLP-table entry math (wave-per-entry) ----------------------
__device__ __forceinline__ float2 mlp_entry(
    int i, int lane, const float* __restrict__ centers,
    const float* __restrict__ W1, const float* __restrict__ b1,
    const float* __restrict__ W2s, const float* __restrict__ b2,
    const float* __restrict__ W3, const float* __restrict__ b3)
{
    float d  = (float)i * (D_MAX / (float)TBL);
    float z1 = b1[lane], u = 0.f;
#pragma unroll
    for (int k = 0; k < K_RBF; ++k) {
        float tc = d - centers[k];
        float e  = exp2f(-tc * tc * LOG2E);       // exp(-t^2)
        float w  = W1[k * H_DIM + lane];
        z1 = fmaf(e, w, z1);
        u  = fmaf(-2.f * tc * e, w, u);
    }
    float s1  = 1.f / (1.f + exp2f(-z1 * LOG2E));
    float h1  = z1 * s1;
    float ds1 = s1 * fmaf(z1, 1.f - s1, 1.f);     // silu'(z1)

    float z2 = b2[lane];
#pragma unroll
    for (int h = 0; h < H_DIM; ++h)
        z2 = fmaf(__shfl(h1, h, 64), W2s[h * 65 + lane], z2);

    float s2  = 1.f / (1.f + exp2f(-z2 * LOG2E));
    float w3  = W3[lane];
    float Fp  = z2 * s2 * w3;
    float dz2 = w3 * s2 * fmaf(z2, 1.f - s2, 1.f);

    float dh1 = 0.f;
#pragma unroll
    for (int j = 0; j < H_DIM; ++j)
        dh1 = fmaf(__shfl(dz2, j, 64), W2s[lane * 65 + j], dh1);

    float Gp = dh1 * ds1 * u;
#pragma unroll
    for (int m = 32; m > 0; m >>= 1) {
        Fp += __shfl_xor(Fp, m, 64);
        Gp += __shfl_xor(Gp, m, 64);
    }
    return make_float2(Fp + b3[0], Gp);
}

// -------- Kernel 1: tabulate F(d)=e_edge(d), G(d)=dE/dd — wave-per-entry ----
__global__ __launch_bounds__(256) void build_table(
    const float* __restrict__ centers,
    const float* __restrict__ W1, const float* __restrict__ b1,
    const float* __restrict__ W2, const float* __restrict__ b2,
    const float* __restrict__ W3, const float* __restrict__ b3,
    float2* __restrict__ tab, float* __restrict__ out, int zero_out_tail)
{
    if (blockIdx.x == 0 && zero_out_tail) {
        int t = threadIdx.x;
        if (t < N_GRAPHS) out[t] = 0.f;                      // energies
        else if (t < OUT_TAIL_N) out[3 * N_NODES + t] = 0.f; // stress+hess
    }

    __shared__ float W2s[H_DIM * 65];
    for (int idx = threadIdx.x; idx < H_DIM * H_DIM; idx += 256)
        W2s[(idx >> 6) * 65 + (idx & 63)] = W2[idx];
    __syncthreads();

    int lane = threadIdx.x & 63;
    int i    = blockIdx.x * 4 + (threadIdx.x >> 6);
    float2 fg = mlp_entry(i, lane, centers, W1, b1, W2s, b2, W3, b3);
    if (lane == 0) tab[i] = fg;
}

// -------- Kernel 2: per-edge compute + static-slot record emission ----------
// No global atomics, no inter-block coordination: block b owns slot run
// recs[c][b][0..32). Rank from one LDS fetch-add per record.
__global__ __launch_bounds__(EDGE_THREADS) void edge_compute(
    const float* __restrict__ pos, const float* __restrict__ bond,
    const int* __restrict__ src, const int* __restrict__ dst,
    const float* __restrict__ volume, const float2* __restrict__ tab,
    float4* __restrict__ recs, int* __restrict__ cnttab,
    float* __restrict__ out)
{
    __shared__ int   cnt[N_CHUNKS];
    __shared__ float red[8][10];

    const int t = threadIdx.x;
    const int b = blockIdx.x;
    if (t < N_CHUNKS) cnt[t] = 0;
    __syncthreads();

    const int e = b * EDGE_THREADS + t;
    const int g = b / BLK_PER_GRAPH;       // edges contiguous per graph

    int si = src[e], di = dst[e];
    float bx = bond[3 * e + 0], by = bond[3 * e + 1], bz = bond[3 * e + 2];
    float dx = bx + pos[3 * di + 0] - pos[3 * si + 0];
    float dy = by + pos[3 * di + 1] - pos[3 * si + 1];
    float dz = bz + pos[3 * di + 2] - pos[3 * si + 2];
    float d  = sqrtf(fmaf(dx, dx, fmaf(dy, dy, fmaf(dz, dz, 1e-12f))));

    float tt  = fminf(d * ((float)TBL / D_MAX), (float)(TBL - 1));
    int   ix  = min((int)tt, TBL - 2);
    float fr  = tt - (float)ix;
    float2 ta = tab[ix], tb2 = tab[ix + 1];
    float F = fmaf(fr, tb2.x - ta.x, ta.x);
    float G = fmaf(fr, tb2.y - ta.y, ta.y);

    float scl = G / d;                     // gbv = (dE/dd)/d * disp
    float gx = scl * dx, gy = scl * dy, gz = scl * dz;

    int c0 = chunk_of(di), c1 = chunk_of(si);
    int r0 = atomicAdd(&cnt[c0], 1);
    int r1 = atomicAdd(&cnt[c1], 1);
    if (r0 < SLOT_CAP)                     // dst gets -g (forces = -gpos)
        recs[((size_t)c0 * EDGE_BLOCKS + b) * SLOT_CAP + r0] =
            make_float4(-gx, -gy, -gz, __int_as_float(di - c0 * CHUNK_NODES));
    if (r1 < SLOT_CAP)                     // src gets +g
        recs[((size_t)c1 * EDGE_BLOCKS + b) * SLOT_CAP + r1] =
            make_float4(gx, gy, gz, __int_as_float(si - c1 * CHUNK_NODES));

    // block-level energy+stress reduce (all edges in block share graph g)
    float vacc[10] = { F,
                       bx * gx, bx * gy, bx * gz,
                       by * gx, by * gy, by * gz,
                       bz * gx, bz * gy, bz * gz };
#pragma unroll
    for (int q = 0; q < 10; ++q) {
        float x = vacc[q];
#pragma unroll
        for (int m = 32; m > 0; m >>= 1) x += __shfl_xor(x, m, 64);
        vacc[q] = x;
    }
    int wave = t >> 6;
    if ((t & 63) == 0)
#pragma unroll
        for (int q = 0; q < 10; ++q) red[wave][q] = vacc[q];
    __syncthreads();

    if (t < N_CHUNKS)
        cnttab[(size_t)t * EDGE_BLOCKS + b] = min(cnt[t], SLOT_CAP);

    if (t < 10) {
        float tot = 0.f;
#pragma unroll
        for (int k = 0; k < 8; ++k) tot += red[k][t];
        if (t == 0) atomicAdd(out + g, tot);
        else {
            float vol = volume[g * NODES_PER_GRAPH];
            atomicAdd(out + OUT_STRESS + g * 9 + (t - 1),
                      tot * (EV_A3_TO_GPA / vol));
        }
    }
}

// -------- Kernel 3: one block per chunk — LDS accumulate over slot space ----
__global__ __launch_bounds__(1024) void scatter_direct(
    const float4* __restrict__ recs, const int* __restrict__ cnttab,
    float* __restrict__ out)
{
    __shared__ float acc[CHUNK_FLOATS];     // 2.3 KB
    __shared__ int   cl[EDGE_BLOCKS];       // 6 KB count row
    const int t = threadIdx.x;
    const int c = blockIdx.x;
    if (t < CHUNK_FLOATS) acc[t] = 0.f;
    for (int j = t; j < EDGE_BLOCKS; j += 1024)
        cl[j] = cnttab[(size_t)c * EDGE_BLOCKS + j];
    __syncthreads();

    const float4* seg = recs + (size_t)c * EDGE_BLOCKS * SLOT_CAP;
#pragma unroll 4
    for (int j = t; j < EDGE_BLOCKS * SLOT_CAP; j += 1024) {
        int bb = j >> CAP_SHIFT;
        int s  = j & (SLOT_CAP - 1);
        if (s < cl[bb]) {                   // only valid slots are fetched
            float4 rec = seg[j];
            int li = 3 * __float_as_int(rec.w);
            atomicAdd(&acc[li + 0], rec.x);
            atomicAdd(&acc[li + 1], rec.y);
            atomicAdd(&acc[li + 2], rec.z);
        }
    }
    __syncthreads();

    if (t < CHUNK_FLOATS)
        out[OUT_FORCES + c * CHUNK_FLOATS + t] = acc[t];
}

// -------- Fallback (ws too small): device-atomic path ----------
__global__ __launch_bounds__(256) void edge_fallback(
    const float* __restrict__ pos, const float* __restrict__ bond,
    const int* __restrict__ src, const int* __restrict__ dst,
    const float* __restrict__ volume, const float2* __restrict__ tab,
    float* __restrict__ out)
{
    __shared__ float red[4][10];
    int lb = (blockIdx.x & 7) * (EDGES_PER_GRAPH / 256) + (blockIdx.x >> 3);
    int g  = blockIdx.x & 7;
    int e  = lb * 256 + threadIdx.x;

    int si = src[e], di = dst[e];
    float bx = bond[3 * e + 0], by = bond[3 * e + 1], bz = bond[3 * e + 2];
    float dx = bx + pos[3 * di + 0] - pos[3 * si + 0];
    float dy = by + pos[3 * di + 1] - pos[3 * si + 1];
    float dz = bz + pos[3 * di + 2] - pos[3 * si + 2];
    float d  = sqrtf(fmaf(dx, dx, fmaf(dy, dy, fmaf(dz, dz, 1e-12f))));

    float tt  = fminf(d * ((float)TBL / D_MAX), (float)(TBL - 1));
    int   ix  = min((int)tt, TBL - 2);
    float fr  = tt - (float)ix;
    float2 ta = tab[ix], tb2 = tab[ix + 1];
    float F = fmaf(fr, tb2.x - ta.x, ta.x);
    float G = fmaf(fr, tb2.y - ta.y, ta.y);
    float scl = G / d;
    float gx = scl * dx, gy = scl * dy, gz = scl * dz;

    float* forces = out + OUT_FORCES;
    atomicAdd(forces + 3 * di + 0, -gx);
    atomicAdd(forces + 3 * di + 1, -gy);
    atomicAdd(forces + 3 * di + 2, -gz);
    atomicAdd(forces + 3 * si + 0,  gx);
    atomicAdd(forces + 3 * si + 1,  gy);
    atomicAdd(forces + 3 * si + 2,  gz);

    float v[10] = { F,
                    bx * gx, bx * gy, bx * gz,
                    by * gx, by * gy, by * gz,
                    bz * gx, bz * gy, bz * gz };
#pragma unroll
    for (int q = 0; q < 10; ++q) {
        float x = v[q];
#pragma unroll
        for (int m = 32; m > 0; m >>= 1) x += __shfl_xor(x, m, 64);
        v[q] = x;
    }
    int wave = threadIdx.x >> 6;
    if ((threadIdx.x & 63) == 0)
#pragma unroll
        for (int q = 0; q < 10; ++q) red[wave][q] = v[q];
    __syncthreads();
    if (threadIdx.x < 10) {
        float tot = red[0][threadIdx.x] + red[1][threadIdx.x]
                  + red[2][threadIdx.x] + red[3][threadIdx.x];
        if (threadIdx.x == 0) atomicAdd(out + g, tot);
        else {
            float vol = volume[g * NODES_PER_GRAPH];
            atomicAdd(out + OUT_STRESS + g * 9 + (threadIdx.x - 1),
                      tot * (EV_A3_TO_GPA / vol));
        }
    }
}

extern "C" void kernel_launch(void* const* d_in, const int* in_sizes, int n_in,
                              void* d_out, int out_size, void* d_ws, size_t ws_size,
                              hipStream_t stream)
{
    const float* pos     = (const float*)d_in[0];
    const float* bond    = (const float*)d_in[1];
    const int*   src     = (const int*)d_in[2];
    const int*   dst     = (const int*)d_in[3];
    // d_in[4] = edge_graph (implicit: edges contiguous per graph)
    const float* volume  = (const float*)d_in[5];
    const float* centers = (const float*)d_in[6];
    const float* W1 = (const float*)d_in[7];
    const float* b1 = (const float*)d_in[8];
    const float* W2 = (const float*)d_in[9];
    const float* b2 = (const float*)d_in[10];
    const float* W3 = (const float*)d_in[11];
    const float* b3 = (const float*)d_in[12];
    float*  out    = (float*)d_out;
    char*   ws     = (char*)d_ws;
    float2* tab    = (float2*)(ws + OFF_TAB);
    int*    cnttab = (int*)(ws + OFF_CNT);
    float4* recs   = (float4*)(ws + OFF_REC);

    if (ws_size >= WS_NEED) {
        build_table<<<TBL / 4, 256, 0, stream>>>(centers, W1, b1, W2, b2, W3, b3,
                                                 tab, out, 1);
        edge_compute<<<EDGE_BLOCKS, EDGE_THREADS, 0, stream>>>(
            pos, bond, src, dst, volume, tab, recs, cnttab, out);
        scatter_direct<<<N_CHUNKS, 1024, 0, stream>>>(recs, cnttab, out);
    } else {
        hipMemsetAsync(d_out, 0, (size_t)out_size * sizeof(float), stream);
        build_table<<<TBL / 4, 256, 0, stream>>>(centers, W1, b1, W2, b2, W3, b3,
                                                 tab, out, 0);
        edge_fallback<<<N_EDGES / 256, 256, 0, stream>>>(
            pos, bond, src, dst, volume, tab, out);
    }
}

// Round 7
// 154.443 us; speedup vs baseline: 1.2724x; 1.0334x over previous
//
#include <hip/hip_runtime.h>
#include <math.h>

#define K_RBF 32
#define H_DIM 64
#define TBL 4096
#define D_MAX 16.0f
#define N_NODES 49152
#define N_EDGES 786432
#define N_GRAPHS 8
#define NODES_PER_GRAPH 6144
#define EV_A3_TO_GPA 160.21766208f
#define LOG2E 1.44269504088896f

// out layout: energies[8] | forces[147456] | stresses[72] | hessian[1]
#define OUT_FORCES 8
#define OUT_STRESS 147464
#define OUT_TAIL_N 81

// force binning: 256 chunks x 192 nodes
#define CHUNK_NODES  192
#define CHUNK_FLOATS 576
#define N_CHUNKS     256

// edge geometry: 512 blocks x 512 thr x 3 edges -> exactly 2 blocks/CU
#define EDGE_BLOCKS   512
#define EDGE_THREADS  512
#define EDGES_PER_THREAD 3
#define EDGES_PER_BLOCK (EDGE_THREADS * EDGES_PER_THREAD)   // 1536
#define EDGES_PER_GRAPH (N_EDGES / N_GRAPHS)                // 98304
#define BLK_PER_GRAPH 64                                    // 98304 / 1536

// static slot ownership: recs[chunk][block][SLOT_CAP]; per-(c,b) lambda = 12
// (3072 records / 256 chunks). cap 40 -> Poisson overflow ~4e-6 over the
// fixed input graph. No global atomics, no cross-block slot exchange.
#define SLOT_CAP   40

// scatter: 16 lanes per (chunk,block) run, prefix-only reads
#define LANES_PER_RUN 16
#define RUNS_PER_PASS 64          // 1024 thr / 16
#define SCT_PASSES    8           // 512 runs / 64

// ws layout (bytes): tab 32 KB | cnttab 512 KB | records 83.9 MB
#define OFF_TAB 0u
#define OFF_CNT 32768u
#define OFF_REC (32768u + (unsigned)(N_CHUNKS * EDGE_BLOCKS * 4))   // 557056
#define WS_NEED ((size_t)OFF_REC + (size_t)N_CHUNKS * EDGE_BLOCKS * SLOT_CAP * 16u)

// chunk index: node/192 = (node>>6)/3 via mul-shift (exact for node < 49152)
__device__ __forceinline__ int chunk_of(int node) {
    return (int)((unsigned)((node >> 6) * 683) >> 11);
}

// -------- shared MLP-table entry math (wave-per-entry) ----------------------
__device__ __forceinline__ float2 mlp_entry(
    int i, int lane, const float* __restrict__ centers,
    const float* __restrict__ W1, const float* __restrict__ b1,
    const float* __restrict__ W2s, const float* __restrict__ b2,
    const float* __restrict__ W3, const float* __restrict__ b3)
{
    float d  = (float)i * (D_MAX / (float)TBL);
    float z1 = b1[lane], u = 0.f;
#pragma unroll
    for (int k = 0; k < K_RBF; ++k) {
        float tc = d - centers[k];
        float e  = exp2f(-tc * tc * LOG2E);       // exp(-t^2)
        float w  = W1[k * H_DIM + lane];
        z1 = fmaf(e, w, z1);
        u  = fmaf(-2.f * tc * e, w, u);
    }
    float s1  = 1.f / (1.f + exp2f(-z1 * LOG2E));
    float h1  = z1 * s1;
    float ds1 = s1 * fmaf(z1, 1.f - s1, 1.f);     // silu'(z1)

    float z2 = b2[lane];
#pragma unroll
    for (int h = 0; h < H_DIM; ++h)
        z2 = fmaf(__shfl(h1, h, 64), W2s[h * 65 + lane], z2);

    float s2  = 1.f / (1.f + exp2f(-z2 * LOG2E));
    float w3  = W3[lane];
    float Fp  = z2 * s2 * w3;
    float dz2 = w3 * s2 * fmaf(z2, 1.f - s2, 1.f);

    float dh1 = 0.f;
#pragma unroll
    for (int j = 0; j < H_DIM; ++j)
        dh1 = fmaf(__shfl(dz2, j, 64), W2s[lane * 65 + j], dh1);

    float Gp = dh1 * ds1 * u;
#pragma unroll
    for (int m = 32; m > 0; m >>= 1) {
        Fp += __shfl_xor(Fp, m, 64);
        Gp += __shfl_xor(Gp, m, 64);
    }
    return make_float2(Fp + b3[0], Gp);
}

// -------- Kernel 1: tabulate F(d)=e_edge(d), G(d)=dE/dd — wave-per-entry ----
__global__ __launch_bounds__(256) void build_table(
    const float* __restrict__ centers,
    const float* __restrict__ W1, const float* __restrict__ b1,
    const float* __restrict__ W2, const float* __restrict__ b2,
    const float* __restrict__ W3, const float* __restrict__ b3,
    float2* __restrict__ tab, float* __restrict__ out, int zero_out_tail)
{
    if (blockIdx.x == 0 && zero_out_tail) {
        int t = threadIdx.x;
        if (t < N_GRAPHS) out[t] = 0.f;                      // energies
        else if (t < OUT_TAIL_N) out[3 * N_NODES + t] = 0.f; // stress+hess
    }

    __shared__ float W2s[H_DIM * 65];
    for (int idx = threadIdx.x; idx < H_DIM * H_DIM; idx += 256)
        W2s[(idx >> 6) * 65 + (idx & 63)] = W2[idx];
    __syncthreads();

    int lane = threadIdx.x & 63;
    int i    = blockIdx.x * 4 + (threadIdx.x >> 6);
    float2 fg = mlp_entry(i, lane, centers, W1, b1, W2s, b2, W3, b3);
    if (lane == 0) tab[i] = fg;
}

// -------- Kernel 2: per-edge compute + static-slot record emission ----------
// Block b owns slot run recs[c][b][0..SLOT_CAP). Rank from one LDS fetch-add
// per record. 3 independent edges per thread for ILP.
__global__ __launch_bounds__(EDGE_THREADS) void edge_compute(
    const float* __restrict__ pos, const float* __restrict__ bond,
    const int* __restrict__ src, const int* __restrict__ dst,
    const float* __restrict__ volume, const float2* __restrict__ tab,
    float4* __restrict__ recs, int* __restrict__ cnttab,
    float* __restrict__ out)
{
    __shared__ int   cnt[N_CHUNKS];
    __shared__ float red[8][10];

    const int t = threadIdx.x;
    const int b = blockIdx.x;
    if (t < N_CHUNKS) cnt[t] = 0;
    __syncthreads();

    const int g = b >> 6;                  // 64 blocks per graph
    const int base_e = b * EDGES_PER_BLOCK;

    float vacc[10];
#pragma unroll
    for (int q = 0; q < 10; ++q) vacc[q] = 0.f;

#pragma unroll
    for (int i = 0; i < EDGES_PER_THREAD; ++i) {
        int e  = base_e + i * EDGE_THREADS + t;
        int si = src[e], di = dst[e];
        float bx = bond[3 * e + 0], by = bond[3 * e + 1], bz = bond[3 * e + 2];
        float dx = bx + pos[3 * di + 0] - pos[3 * si + 0];
        float dy = by + pos[3 * di + 1] - pos[3 * si + 1];
        float dz = bz + pos[3 * di + 2] - pos[3 * si + 2];
        float d  = sqrtf(fmaf(dx, dx, fmaf(dy, dy, fmaf(dz, dz, 1e-12f))));

        float tt  = fminf(d * ((float)TBL / D_MAX), (float)(TBL - 1));
        int   ix  = min((int)tt, TBL - 2);
        float fr  = tt - (float)ix;
        float2 ta = tab[ix], tb2 = tab[ix + 1];
        float F = fmaf(fr, tb2.x - ta.x, ta.x);
        float G = fmaf(fr, tb2.y - ta.y, ta.y);

        float scl = G / d;                 // gbv = (dE/dd)/d * disp
        float gx = scl * dx, gy = scl * dy, gz = scl * dz;

        int c0 = chunk_of(di), c1 = chunk_of(si);
        int r0 = atomicAdd(&cnt[c0], 1);
        int r1 = atomicAdd(&cnt[c1], 1);
        if (r0 < SLOT_CAP)                 // dst gets -g (forces = -gpos)
            recs[((size_t)c0 * EDGE_BLOCKS + b) * SLOT_CAP + r0] =
                make_float4(-gx, -gy, -gz, __int_as_float(di - c0 * CHUNK_NODES));
        if (r1 < SLOT_CAP)                 // src gets +g
            recs[((size_t)c1 * EDGE_BLOCKS + b) * SLOT_CAP + r1] =
                make_float4(gx, gy, gz, __int_as_float(si - c1 * CHUNK_NODES));

        vacc[0] += F;
        vacc[1] = fmaf(bx, gx, vacc[1]); vacc[2] = fmaf(bx, gy, vacc[2]);
        vacc[3] = fmaf(bx, gz, vacc[3]); vacc[4] = fmaf(by, gx, vacc[4]);
        vacc[5] = fmaf(by, gy, vacc[5]); vacc[6] = fmaf(by, gz, vacc[6]);
        vacc[7] = fmaf(bz, gx, vacc[7]); vacc[8] = fmaf(bz, gy, vacc[8]);
        vacc[9] = fmaf(bz, gz, vacc[9]);
    }

    // block-level energy+stress reduce (all edges in block share graph g)
#pragma unroll
    for (int q = 0; q < 10; ++q) {
        float x = vacc[q];
#pragma unroll
        for (int m = 32; m > 0; m >>= 1) x += __shfl_xor(x, m, 64);
        vacc[q] = x;
    }
    int wave = t >> 6;
    if ((t & 63) == 0)
#pragma unroll
        for (int q = 0; q < 10; ++q) red[wave][q] = vacc[q];
    __syncthreads();

    if (t < N_CHUNKS)
        cnttab[(size_t)t * EDGE_BLOCKS + b] = min(cnt[t], SLOT_CAP);

    if (t < 10) {
        float tot = 0.f;
#pragma unroll
        for (int k = 0; k < 8; ++k) tot += red[k][t];
        if (t == 0) atomicAdd(out + g, tot);
        else {
            float vol = volume[g * NODES_PER_GRAPH];
            atomicAdd(out + OUT_STRESS + g * 9 + (t - 1),
                      tot * (EV_A3_TO_GPA / vol));
        }
    }
}

// -------- Kernel 3: one block per chunk — prefix-only reads, LDS accumulate -
// 16 lanes per (chunk,block) run walk only the valid prefix [0, cnt);
// lambda=12 < 16 so usually a single iteration. Work ~ valid records.
__global__ __launch_bounds__(1024) void scatter_direct(
    const float4* __restrict__ recs, const int* __restrict__ cnttab,
    float* __restrict__ out)
{
    __shared__ float acc[CHUNK_FLOATS];     // 2.3 KB
    __shared__ int   cl[EDGE_BLOCKS];       // 2 KB count row
    const int t = threadIdx.x;
    const int c = blockIdx.x;
    if (t < CHUNK_FLOATS) acc[t] = 0.f;
    if (t < EDGE_BLOCKS) cl[t] = cnttab[(size_t)c * EDGE_BLOCKS + t];
    __syncthreads();

    const float4* seg = recs + (size_t)c * EDGE_BLOCKS * SLOT_CAP;
    const int sub = t & (LANES_PER_RUN - 1);
    const int rr0 = t >> 4;                 // run within pass
#pragma unroll
    for (int p = 0; p < SCT_PASSES; ++p) {
        int rr  = p * RUNS_PER_PASS + rr0;
        int n   = cl[rr];
        const float4* run = seg + (size_t)rr * SLOT_CAP;
        for (int s = sub; s < n; s += LANES_PER_RUN) {
            float4 rec = run[s];
            int li = 3 * __float_as_int(rec.w);
            atomicAdd(&acc[li + 0], rec.x);
            atomicAdd(&acc[li + 1], rec.y);
            atomicAdd(&acc[li + 2], rec.z);
        }
    }
    __syncthreads();

    if (t < CHUNK_FLOATS)
        out[OUT_FORCES + c * CHUNK_FLOATS + t] = acc[t];
}

// -------- Fallback (ws too small): device-atomic path ----------
__global__ __launch_bounds__(256) void edge_fallback(
    const float* __restrict__ pos, const float* __restrict__ bond,
    const int* __restrict__ src, const int* __restrict__ dst,
    const float* __restrict__ volume, const float2* __restrict__ tab,
    float* __restrict__ out)
{
    __shared__ float red[4][10];
    int lb = (blockIdx.x & 7) * (EDGES_PER_GRAPH / 256) + (blockIdx.x >> 3);
    int g  = blockIdx.x & 7;
    int e  = lb * 256 + threadIdx.x;

    int si = src[e], di = dst[e];
    float bx = bond[3 * e + 0], by = bond[3 * e + 1], bz = bond[3 * e + 2];
    float dx = bx + pos[3 * di + 0] - pos[3 * si + 0];
    float dy = by + pos[3 * di + 1] - pos[3 * si + 1];
    float dz = bz + pos[3 * di + 2] - pos[3 * si + 2];
    float d  = sqrtf(fmaf(dx, dx, fmaf(dy, dy, fmaf(dz, dz, 1e-12f))));

    float tt  = fminf(d * ((float)TBL / D_MAX), (float)(TBL - 1));
    int   ix  = min((int)tt, TBL - 2);
    float fr  = tt - (float)ix;
    float2 ta = tab[ix], tb2 = tab[ix + 1];
    float F = fmaf(fr, tb2.x - ta.x, ta.x);
    float G = fmaf(fr, tb2.y - ta.y, ta.y);
    float scl = G / d;
    float gx = scl * dx, gy = scl * dy, gz = scl * dz;

    float* forces = out + OUT_FORCES;
    atomicAdd(forces + 3 * di + 0, -gx);
    atomicAdd(forces + 3 * di + 1, -gy);
    atomicAdd(forces + 3 * di + 2, -gz);
    atomicAdd(forces + 3 * si + 0,  gx);
    atomicAdd(forces + 3 * si + 1,  gy);
    atomicAdd(forces + 3 * si + 2,  gz);

    float v[10] = { F,
                    bx * gx, bx * gy, bx * gz,
                    by * gx, by * gy, by * gz,
                    bz * gx, bz * gy, bz * gz };
#pragma unroll
    for (int q = 0; q < 10; ++q) {
        float x = v[q];
#pragma unroll
        for (int m = 32; m > 0; m >>= 1) x += __shfl_xor(x, m, 64);
        v[q] = x;
    }
    int wave = threadIdx.x >> 6;
    if ((threadIdx.x & 63) == 0)
#pragma unroll
        for (int q = 0; q < 10; ++q) red[wave][q] = v[q];
    __syncthreads();
    if (threadIdx.x < 10) {
        float tot = red[0][threadIdx.x] + red[1][threadIdx.x]
                  + red[2][threadIdx.x] + red[3][threadIdx.x];
        if (threadIdx.x == 0) atomicAdd(out + g, tot);
        else {
            float vol = volume[g * NODES_PER_GRAPH];
            atomicAdd(out + OUT_STRESS + g * 9 + (threadIdx.x - 1),
                      tot * (EV_A3_TO_GPA / vol));
        }
    }
}

extern "C" void kernel_launch(void* const* d_in, const int* in_sizes, int n_in,
                              void* d_out, int out_size, void* d_ws, size_t ws_size,
                              hipStream_t stream)
{
    const float* pos     = (const float*)d_in[0];
    const float* bond    = (const float*)d_in[1];
    const int*   src     = (const int*)d_in[2];
    const int*   dst     = (const int*)d_in[3];
    // d_in[4] = edge_graph (implicit: edges contiguous per graph)
    const float* volume  = (const float*)d_in[5];
    const float* centers = (const float*)d_in[6];
    const float* W1 = (const float*)d_in[7];
    const float* b1 = (const float*)d_in[8];
    const float* W2 = (const float*)d_in[9];
    const float* b2 = (const float*)d_in[10];
    const float* W3 = (const float*)d_in[11];
    const float* b3 = (const float*)d_in[12];
    float*  out    = (float*)d_out;
    char*   ws     = (char*)d_ws;
    float2* tab    = (float2*)(ws + OFF_TAB);
    int*    cnttab = (int*)(ws + OFF_CNT);
    float4* recs   = (float4*)(ws + OFF_REC);

    if (ws_size >= WS_NEED) {
        build_table<<<TBL / 4, 256, 0, stream>>>(centers, W1, b1, W2, b2, W3, b3,
                                                 tab, out, 1);
        edge_compute<<<EDGE_BLOCKS, EDGE_THREADS, 0, stream>>>(
            pos, bond, src, dst, volume, tab, recs, cnttab, out);
        scatter_direct<<<N_CHUNKS, 1024, 0, stream>>>(recs, cnttab, out);
    } else {
        hipMemsetAsync(d_out, 0, (size_t)out_size * sizeof(float), stream);
        build_table<<<TBL / 4, 256, 0, stream>>>(centers, W1, b1, W2, b2, W3, b3,
                                                 tab, out, 0);
        edge_fallback<<<N_EDGES / 256, 256, 0, stream>>>(
            pos, bond, src, dst, volume, tab, out);
    }
}